// Round 1
// baseline (349.598 us; speedup 1.0000x reference)
//
#include <hip/hip_runtime.h>
#include <hip/hip_bf16.h>

typedef unsigned short u16;
typedef unsigned int   u32;

using bf16x8 = __attribute__((ext_vector_type(8))) short;  // 8 bf16 in 4 VGPRs
using f32x4  = __attribute__((ext_vector_type(4))) float;  // MFMA accumulator

#define NB 32
#define NP 1024
#define ND 256

__device__ __forceinline__ u16 f2bf(float x){
  u32 u = __float_as_uint(x);
  u += 0x7FFFu + ((u >> 16) & 1u);   // round-to-nearest-even
  return (u16)(u >> 16);
}

// ---------------- prep 1: Pbf = bf16(P), sbv[row] = P[row,:] . wb ----------------
__global__ void prep_rows(const float* __restrict__ P, const float* __restrict__ wi,
                          u16* __restrict__ Pbf, float* __restrict__ sbv){
  const int row  = blockIdx.x * 4 + (threadIdx.x >> 6);   // one wave per row
  const int lane = threadIdx.x & 63;
  const float4 p  = *(const float4*)(P  + (size_t)row * ND + lane * 4);
  const float4 wb = *(const float4*)(wi + ND + lane * 4);  // wb = wi[256:512]
  ushort4 pb;
  pb.x = f2bf(p.x); pb.y = f2bf(p.y); pb.z = f2bf(p.z); pb.w = f2bf(p.w);
  *(ushort4*)(Pbf + (size_t)row * ND + lane * 4) = pb;
  float s = p.x*wb.x + p.y*wb.y + p.z*wb.z + p.w*wb.w;
  #pragma unroll
  for (int m = 1; m < 64; m <<= 1) s += __shfl_xor(s, m, 64);
  if (lane == 0) sbv[row] = s;
}

// ---------------- prep 2: Wt[n][k] = bf16(w{1,2,3}[k][n%256]), n in [0,768) ------
__global__ void prep_w(const float* __restrict__ w1, const float* __restrict__ w2,
                       const float* __restrict__ w3, u16* __restrict__ Wt){
  const int n = blockIdx.x;                       // 0..767
  const float* w = (n < 256) ? w1 : ((n < 512) ? w2 : w3);
  const int nl = n & 255;
  for (int k = threadIdx.x; k < 512; k += blockDim.x)
    Wt[(size_t)n * 512 + k] = f2bf(w[(size_t)k * 256 + nl]);
}

// ---------------- attention: flash-style, QBLK=64 (4 waves x 16 rows), KBLK=64 ---
__launch_bounds__(256, 2)
__global__ void attn_kernel(const float* __restrict__ P, const float* __restrict__ wi,
                            const u16* __restrict__ Pbf, const float* __restrict__ sbv,
                            u16* __restrict__ attnb){
  const int b    = blockIdx.y;
  const int q0   = blockIdx.x * 64;
  const int tid  = threadIdx.x;
  const int wave = tid >> 6, lane = tid & 63, lo = lane & 15, hi = lane >> 4;

  __shared__ __align__(16) u16 Kt[64][264];      // key-major, pitch 264 (b128 conflict-free)
  __shared__ __align__(16) u16 Vt[256 * 64];     // d-major (V^T), XOR-swizzled
  __shared__ __align__(16) u16 Sp[4][16][72];    // per-wave P-tile repack
  __shared__ float sbt[64];

  // ---- Q fragments (A-operand): q = P * wc, converted to bf16, kept in regs ----
  bf16x8 qf[8];
  {
    const int qrow = q0 + wave * 16 + lo;
    const float* prow = P  + ((size_t)b * NP + qrow) * ND;
    const float* wcp  = wi + 512;
    #pragma unroll
    for (int c = 0; c < 8; ++c){
      const int d0 = 32 * c + 8 * hi;
      float4 a  = *(const float4*)(prow + d0);
      float4 a2 = *(const float4*)(prow + d0 + 4);
      float4 wa  = *(const float4*)(wcp + d0);
      float4 wa2 = *(const float4*)(wcp + d0 + 4);
      bf16x8 q;
      q[0]=(short)f2bf(a.x*wa.x);  q[1]=(short)f2bf(a.y*wa.y);
      q[2]=(short)f2bf(a.z*wa.z);  q[3]=(short)f2bf(a.w*wa.w);
      q[4]=(short)f2bf(a2.x*wa2.x); q[5]=(short)f2bf(a2.y*wa2.y);
      q[6]=(short)f2bf(a2.z*wa2.z); q[7]=(short)f2bf(a2.w*wa2.w);
      qf[c] = q;
    }
  }

  f32x4 of[16];
  #pragma unroll
  for (int t = 0; t < 16; ++t) of[t] = (f32x4){0.f,0.f,0.f,0.f};
  float mx[4] = {-1e30f,-1e30f,-1e30f,-1e30f};
  float ls[4] = {0.f,0.f,0.f,0.f};

  for (int kt = 0; kt < 16; ++kt){
    const int kbase = kt * 64;

    // ---- stage K tile (row-major) from global, coalesced 16B ----
    {
      const u16* src = Pbf + ((size_t)b * NP + kbase) * ND;
      #pragma unroll
      for (int it = 0; it < 8; ++it){
        int cc = tid + 256 * it;            // 0..2047 = 64 rows x 32 chunks
        int row = cc >> 5, c8 = cc & 31;
        uint4 v = *(const uint4*)(src + (size_t)row * ND + c8 * 8);
        *(uint4*)&Kt[row][c8 * 8] = v;
      }
      if (tid < 64) sbt[tid] = sbv[(size_t)b * NP + kbase + tid];
    }
    __syncthreads();

    // ---- build V^T in LDS (swizzled) from Kt ----
    #pragma unroll
    for (int it = 0; it < 8; ++it){
      int cc = tid + 256 * it;              // key = lane, d-chunk = wave+4*it
      int key = cc & 63;
      int d0  = (cc >> 6) * 8;
      uint4 v = *(const uint4*)&Kt[key][d0];
      const u16* vs = (const u16*)&v;
      #pragma unroll
      for (int j = 0; j < 8; ++j){
        int d = d0 + j;
        Vt[((d << 6) + key) ^ ((d & 7) << 3)] = vs[j];
      }
    }

    // ---- S = Q K^T (4 col-tiles of 16x16, K-loop over d=256) ----
    f32x4 s[4];
    #pragma unroll
    for (int nt = 0; nt < 4; ++nt){
      f32x4 acc = (f32x4){0.f,0.f,0.f,0.f};
      #pragma unroll
      for (int c = 0; c < 8; ++c){
        bf16x8 kf = *(const bf16x8*)&Kt[nt * 16 + lo][32 * c + 8 * hi];
        acc = __builtin_amdgcn_mfma_f32_16x16x32_bf16(qf[c], kf, acc, 0, 0, 0);
      }
      s[nt] = acc;
    }
    // add sb[j] (sa cancels in softmax)
    #pragma unroll
    for (int nt = 0; nt < 4; ++nt){
      float sv = sbt[nt * 16 + lo];
      #pragma unroll
      for (int r = 0; r < 4; ++r) s[nt][r] += sv;
    }

    // ---- online softmax (rows live in 16-lane groups, reg r = row 4*hi+r) ----
    float scale[4];
    #pragma unroll
    for (int r = 0; r < 4; ++r){
      float v = fmaxf(fmaxf(s[0][r], s[1][r]), fmaxf(s[2][r], s[3][r]));
      v = fmaxf(v, __shfl_xor(v, 1, 64));
      v = fmaxf(v, __shfl_xor(v, 2, 64));
      v = fmaxf(v, __shfl_xor(v, 4, 64));
      v = fmaxf(v, __shfl_xor(v, 8, 64));
      float mnew = fmaxf(mx[r], v);
      scale[r] = __expf(mx[r] - mnew);
      mx[r] = mnew;
      float rs = 0.f;
      #pragma unroll
      for (int nt = 0; nt < 4; ++nt){
        float p = __expf(s[nt][r] - mnew);
        s[nt][r] = p; rs += p;
      }
      rs += __shfl_xor(rs, 1, 64);
      rs += __shfl_xor(rs, 2, 64);
      rs += __shfl_xor(rs, 4, 64);
      rs += __shfl_xor(rs, 8, 64);
      ls[r] = ls[r] * scale[r] + rs;
    }
    #pragma unroll
    for (int t = 0; t < 16; ++t){
      #pragma unroll
      for (int r = 0; r < 4; ++r) of[t][r] *= scale[r];
    }
    // repack P-tile to LDS in A-fragment-friendly layout
    #pragma unroll
    for (int nt = 0; nt < 4; ++nt)
      #pragma unroll
      for (int r = 0; r < 4; ++r)
        Sp[wave][4 * hi + r][16 * nt + lo] = f2bf(s[nt][r]);

    __syncthreads();   // Vt complete (and Kt free for next stage)

    // ---- O += P V ----
    #pragma unroll
    for (int kk = 0; kk < 2; ++kk){
      bf16x8 pa = *(const bf16x8*)&Sp[wave][lo][32 * kk + 8 * hi];
      #pragma unroll
      for (int t = 0; t < 16; ++t){
        int d = 16 * t + lo;
        int idx = ((d << 6) + 32 * kk + 8 * hi) ^ ((d & 7) << 3);
        bf16x8 vb = *(const bf16x8*)&Vt[idx];
        of[t] = __builtin_amdgcn_mfma_f32_16x16x32_bf16(pa, vb, of[t], 0, 0, 0);
      }
    }
  }

  // ---- epilogue: O /= l, store bf16 ----
  const int qrow = q0 + wave * 16;
  #pragma unroll
  for (int t = 0; t < 16; ++t){
    #pragma unroll
    for (int r = 0; r < 4; ++r){
      float o = of[t][r] / ls[r];
      attnb[((size_t)b * NP + qrow + 4 * hi + r) * ND + 16 * t + lo] = f2bf(o);
    }
  }
}

// ---------------- MLP: Y = [P|attn] @ Wt^T, fused gate epilogue ------------------
__launch_bounds__(256, 2)
__global__ void mlp_kernel(const float* __restrict__ P, const u16* __restrict__ Pbf,
                           const u16* __restrict__ attnb, const u16* __restrict__ Wt,
                           const float* __restrict__ b1, const float* __restrict__ b2,
                           const float* __restrict__ b3, float* __restrict__ out){
  const int m0   = blockIdx.x * 32;
  const int tid  = threadIdx.x;
  const int wave = tid >> 6, lane = tid & 63, lo = lane & 15, hi = lane >> 4;

  __shared__ __align__(16) u16 Xt[32][520];   // 32 rows x 512 (pitch 520, conflict-free)

  #pragma unroll
  for (int it = 0; it < 8; ++it){
    int cc = tid + 256 * it;                  // 32 rows x 64 chunks
    int row = cc >> 6, c8 = cc & 63;
    uint4 v;
    if (c8 < 32) v = *(const uint4*)(Pbf   + ((size_t)(m0 + row)) * ND + c8 * 8);
    else         v = *(const uint4*)(attnb + ((size_t)(m0 + row)) * ND + (c8 - 32) * 8);
    *(uint4*)&Xt[row][c8 * 8] = v;
  }
  __syncthreads();

  f32x4 acc[12][2];
  #pragma unroll
  for (int j = 0; j < 12; ++j){ acc[j][0] = (f32x4){0,0,0,0}; acc[j][1] = (f32x4){0,0,0,0}; }

  for (int c = 0; c < 16; ++c){
    bf16x8 a0 = *(const bf16x8*)&Xt[lo][32 * c + 8 * hi];
    bf16x8 a1 = *(const bf16x8*)&Xt[16 + lo][32 * c + 8 * hi];
    #pragma unroll
    for (int j = 0; j < 12; ++j){
      int n = 16 * (wave + 4 * j) + lo;       // wave-striped n-tiles: triplets stay in-wave
      bf16x8 bfr = *(const bf16x8*)(Wt + (size_t)n * 512 + 32 * c + 8 * hi);
      acc[j][0] = __builtin_amdgcn_mfma_f32_16x16x32_bf16(a0, bfr, acc[j][0], 0, 0, 0);
      acc[j][1] = __builtin_amdgcn_mfma_f32_16x16x32_bf16(a1, bfr, acc[j][1], 0, 0, 0);
    }
  }

  #pragma unroll
  for (int mt = 0; mt < 2; ++mt){
    #pragma unroll
    for (int j = 0; j < 4; ++j){
      const int d = 16 * (wave + 4 * j) + lo;  // d-tile index = wave+4j in [0,16)
      const float bb1 = b1[d], bb2 = b2[d], bb3 = b3[d];
      #pragma unroll
      for (int r = 0; r < 4; ++r){
        const int row = m0 + 16 * mt + 4 * hi + r;
        float y1 = acc[j][mt][r]     + bb1;
        float y2 = acc[j + 4][mt][r] + bb2;
        float y3 = acc[j + 8][mt][r] + bb3;
        float pv = P[(size_t)row * ND + d];
        float e2 = __expf(2.f * y1);
        float z  = (e2 - 1.f) / (e2 + 1.f);          // tanh
        float rr = 1.f / (1.f + __expf(-y2));        // sigmoid
        float ff = 1.f / (1.f + __expf(-y3));        // sigmoid
        out[(size_t)row * ND + d] = rr * pv + ff * z;
      }
    }
  }
}

extern "C" void kernel_launch(void* const* d_in, const int* in_sizes, int n_in,
                              void* d_out, int out_size, void* d_ws, size_t ws_size,
                              hipStream_t stream){
  const float* P  = (const float*)d_in[0];
  const float* wi = (const float*)d_in[1];
  const float* w1 = (const float*)d_in[2];
  const float* w2 = (const float*)d_in[3];
  const float* w3 = (const float*)d_in[4];
  const float* b1 = (const float*)d_in[5];
  const float* b2 = (const float*)d_in[6];
  const float* b3 = (const float*)d_in[7];
  float* out = (float*)d_out;

  char* ws = (char*)d_ws;
  u16*   Pbf   = (u16*)  (ws);                       // 32768*256*2 = 16 MB
  u16*   attnb = (u16*)  (ws + 16777216);            // 16 MB
  u16*   Wt    = (u16*)  (ws + 33554432);            // 768*512*2 = 768 KB
  float* sbv   = (float*)(ws + 34340864);            // 32768*4 = 128 KB

  prep_rows<<<8192, 256, 0, stream>>>(P, wi, Pbf, sbv);
  prep_w<<<768, 256, 0, stream>>>(w1, w2, w3, Wt);
  dim3 ag(16, 32);
  attn_kernel<<<ag, 256, 0, stream>>>(P, wi, Pbf, sbv, attnb);
  mlp_kernel<<<1024, 256, 0, stream>>>(P, Pbf, attnb, Wt, b1, b2, b3, out);
}

// Round 2
// 215.600 us; speedup vs baseline: 1.6215x; 1.6215x over previous
//
#include <hip/hip_runtime.h>
#include <hip/hip_bf16.h>

typedef unsigned short u16;
typedef unsigned int   u32;

using bf16x8 = __attribute__((ext_vector_type(8))) short;  // 8 bf16 in 4 VGPRs
using f32x4  = __attribute__((ext_vector_type(4))) float;  // MFMA accumulator

#define NB 32
#define NP 1024
#define ND 256

__device__ __forceinline__ u16 f2bf(float x){
  u32 u = __float_as_uint(x);
  u += 0x7FFFu + ((u >> 16) & 1u);   // round-to-nearest-even
  return (u16)(u >> 16);
}

__device__ __forceinline__ void glds16(const void* g, void* l){
  __builtin_amdgcn_global_load_lds((const __attribute__((address_space(1))) void*)g,
                                   (__attribute__((address_space(3))) void*)l, 16, 0, 0);
}

// ---------------- prep 1: Pbf = bf16(P), sbv[row] = P[row,:] . wb ----------------
__global__ void prep_rows(const float* __restrict__ P, const float* __restrict__ wi,
                          u16* __restrict__ Pbf, float* __restrict__ sbv){
  const int row  = blockIdx.x * 4 + (threadIdx.x >> 6);   // one wave per row
  const int lane = threadIdx.x & 63;
  const float4 p  = *(const float4*)(P  + (size_t)row * ND + lane * 4);
  const float4 wb = *(const float4*)(wi + ND + lane * 4);  // wb = wi[256:512]
  ushort4 pb;
  pb.x = f2bf(p.x); pb.y = f2bf(p.y); pb.z = f2bf(p.z); pb.w = f2bf(p.w);
  *(ushort4*)(Pbf + (size_t)row * ND + lane * 4) = pb;
  float s = p.x*wb.x + p.y*wb.y + p.z*wb.z + p.w*wb.w;
  #pragma unroll
  for (int m = 1; m < 64; m <<= 1) s += __shfl_xor(s, m, 64);
  if (lane == 0) sbv[row] = s;
}

// ---------------- prep 2: Wt[n][k] = bf16(w{1,2,3}[k][n%256]), n in [0,768) ------
__global__ void prep_w(const float* __restrict__ w1, const float* __restrict__ w2,
                       const float* __restrict__ w3, u16* __restrict__ Wt){
  const int n = blockIdx.x;                       // 0..767
  const float* w = (n < 256) ? w1 : ((n < 512) ? w2 : w3);
  const int nl = n & 255;
  for (int k = threadIdx.x; k < 512; k += blockDim.x)
    Wt[(size_t)n * 512 + k] = f2bf(w[(size_t)k * 256 + nl]);
}

// ---------------- prep 3: PbfT[b][d][j] = Pbf[b][j][d] (64x64 LDS tiles) ---------
__global__ void transpose_p(const u16* __restrict__ Pbf, u16* __restrict__ PbfT){
  const int b = blockIdx.z, jt = blockIdx.x, dt = blockIdx.y;
  __shared__ u16 T[64][72];
  const int tid = threadIdx.x;
  #pragma unroll
  for (int it = 0; it < 2; ++it){
    int cc = tid + 256 * it;               // 0..511: 64 j-rows x 8 chunks
    int j = cc >> 3, c8 = cc & 7;
    uint4 v = *(const uint4*)(Pbf + ((size_t)b * NP + jt * 64 + j) * ND + dt * 64 + c8 * 8);
    *(uint4*)&T[j][c8 * 8] = v;
  }
  __syncthreads();
  #pragma unroll
  for (int it = 0; it < 2; ++it){
    int cc = tid + 256 * it;               // 64 d-rows x 8 chunks
    int d = cc >> 3, c8 = cc & 7;
    u16 tmp[8];
    #pragma unroll
    for (int k = 0; k < 8; ++k) tmp[k] = T[c8 * 8 + k][d];
    *(uint4*)(PbfT + ((size_t)b * ND + dt * 64 + d) * NP + jt * 64 + c8 * 8) = *(uint4*)tmp;
  }
}

// ---------------- attention: flash-style, QBLK=64 (4 waves x 16 rows), KBLK=64 ---
// Kt: 64 rows x 256 d, physical byte = row*512 + (c ^ ((row&7)<<4))
// Vt: 256 d  x  64 j,  physical byte = d*128  + (c ^ ((d&7)<<4))
// Staged via global_load_lds (linear dest) with inverse-swizzled global source.
__launch_bounds__(256, 2)
__global__ void attn_kernel(const float* __restrict__ P, const float* __restrict__ wi,
                            const u16* __restrict__ Pbf, const u16* __restrict__ PbfT,
                            const float* __restrict__ sbv, u16* __restrict__ attnb){
  const int bid  = ((blockIdx.x & 7) << 6) | (blockIdx.x >> 3);  // XCD-contiguous chunks
  const int b    = bid >> 4;
  const int q0   = (bid & 15) << 6;
  const int tid  = threadIdx.x;
  const int wave = tid >> 6, lane = tid & 63, lo = lane & 15, hi = lane >> 4;

  __shared__ __align__(16) u16 KtA[64 * 256];
  __shared__ __align__(16) u16 VtA[256 * 64];
  __shared__ __align__(16) u16 Sp[4][16][72];
  __shared__ float sbt[64];
  char* KtB = (char*)KtA;
  char* VtB = (char*)VtA;

  // ---- Q fragments (A-operand): q = P * wc, bf16, in regs ----
  bf16x8 qf[8];
  {
    const int qrow = q0 + wave * 16 + lo;
    const float* prow = P  + ((size_t)b * NP + qrow) * ND;
    const float* wcp  = wi + 512;
    #pragma unroll
    for (int c = 0; c < 8; ++c){
      const int d0 = 32 * c + 8 * hi;
      float4 a  = *(const float4*)(prow + d0);
      float4 a2 = *(const float4*)(prow + d0 + 4);
      float4 wa  = *(const float4*)(wcp + d0);
      float4 wa2 = *(const float4*)(wcp + d0 + 4);
      bf16x8 q;
      q[0]=(short)f2bf(a.x*wa.x);  q[1]=(short)f2bf(a.y*wa.y);
      q[2]=(short)f2bf(a.z*wa.z);  q[3]=(short)f2bf(a.w*wa.w);
      q[4]=(short)f2bf(a2.x*wa2.x); q[5]=(short)f2bf(a2.y*wa2.y);
      q[6]=(short)f2bf(a2.z*wa2.z); q[7]=(short)f2bf(a2.w*wa2.w);
      qf[c] = q;
    }
  }

  f32x4 of[16];
  #pragma unroll
  for (int t = 0; t < 16; ++t) of[t] = (f32x4){0.f,0.f,0.f,0.f};
  float mx[4] = {-1e30f,-1e30f,-1e30f,-1e30f};
  float ls[4] = {0.f,0.f,0.f,0.f};

  const u16* kslab = Pbf  + (size_t)b * NP * ND;   // row-major [j][d]
  const u16* vslab = PbfT + (size_t)b * ND * NP;   // d-major  [d][j]

  for (int kt = 0; kt < 16; ++kt){
    const int kbase = kt * 64;

    // ---- stage K tile: 8 rounds x (4 waves x 1KB); source pre-swizzled ----
    #pragma unroll
    for (int it = 0; it < 8; ++it){
      int off = it * 4096 + wave * 1024 + lane * 16;        // physical LDS byte
      int row = off >> 9;
      int cl  = (off & 511) ^ ((row & 7) << 4);             // logical byte in row
      const char* g = (const char*)(kslab + (size_t)(kbase + row) * ND) + cl;
      glds16(g, KtB + it * 4096 + wave * 1024);
    }
    // ---- stage V^T tile ----
    #pragma unroll
    for (int it = 0; it < 8; ++it){
      int off = it * 4096 + wave * 1024 + lane * 16;
      int d   = off >> 7;
      int cl  = (off & 127) ^ ((d & 7) << 4);
      const char* g = (const char*)(vslab + (size_t)d * NP + kbase) + cl;
      glds16(g, VtB + it * 4096 + wave * 1024);
    }
    if (tid < 64) sbt[tid] = sbv[(size_t)b * NP + kbase + tid];
    __syncthreads();   // vmcnt(0) drain + barrier: tiles visible

    // ---- S = Q K^T ----
    f32x4 s[4];
    #pragma unroll
    for (int nt = 0; nt < 4; ++nt){
      f32x4 acc = (f32x4){0.f,0.f,0.f,0.f};
      #pragma unroll
      for (int c = 0; c < 8; ++c){
        int row = nt * 16 + lo;
        int pb  = row * 512 + ((64 * c + 16 * hi) ^ ((row & 7) << 4));
        bf16x8 kf = *(const bf16x8*)(KtB + pb);
        acc = __builtin_amdgcn_mfma_f32_16x16x32_bf16(qf[c], kf, acc, 0, 0, 0);
      }
      s[nt] = acc;
    }
    // add sb[j] (sa cancels in softmax)
    #pragma unroll
    for (int nt = 0; nt < 4; ++nt){
      float sv = sbt[nt * 16 + lo];
      #pragma unroll
      for (int r = 0; r < 4; ++r) s[nt][r] += sv;
    }

    // ---- online softmax (row i = 4*hi+r lives across the 16 lo-lanes) ----
    float scale[4];
    #pragma unroll
    for (int r = 0; r < 4; ++r){
      float v = fmaxf(fmaxf(s[0][r], s[1][r]), fmaxf(s[2][r], s[3][r]));
      v = fmaxf(v, __shfl_xor(v, 1, 64));
      v = fmaxf(v, __shfl_xor(v, 2, 64));
      v = fmaxf(v, __shfl_xor(v, 4, 64));
      v = fmaxf(v, __shfl_xor(v, 8, 64));
      float mnew = fmaxf(mx[r], v);
      scale[r] = __expf(mx[r] - mnew);
      mx[r] = mnew;
      float rs = 0.f;
      #pragma unroll
      for (int nt = 0; nt < 4; ++nt){
        float p = __expf(s[nt][r] - mnew);
        s[nt][r] = p; rs += p;
      }
      rs += __shfl_xor(rs, 1, 64);
      rs += __shfl_xor(rs, 2, 64);
      rs += __shfl_xor(rs, 4, 64);
      rs += __shfl_xor(rs, 8, 64);
      ls[r] = ls[r] * scale[r] + rs;
    }
    #pragma unroll
    for (int t = 0; t < 16; ++t){
      #pragma unroll
      for (int r = 0; r < 4; ++r) of[t][r] *= scale[r];
    }
    // repack P-tile (per-wave buffer; within-wave dependency, no barrier needed)
    #pragma unroll
    for (int nt = 0; nt < 4; ++nt)
      #pragma unroll
      for (int r = 0; r < 4; ++r)
        Sp[wave][4 * hi + r][16 * nt + lo] = f2bf(s[nt][r]);

    // ---- O += P V ----
    #pragma unroll
    for (int kk = 0; kk < 2; ++kk){
      bf16x8 pa = *(const bf16x8*)&Sp[wave][lo][32 * kk + 8 * hi];
      #pragma unroll
      for (int t = 0; t < 16; ++t){
        int d  = 16 * t + lo;
        int pb = d * 128 + ((64 * kk + 16 * hi) ^ ((d & 7) << 4));
        bf16x8 vb = *(const bf16x8*)(VtB + pb);
        of[t] = __builtin_amdgcn_mfma_f32_16x16x32_bf16(pa, vb, of[t], 0, 0, 0);
      }
    }
    __syncthreads();   // all waves done reading before next stage overwrites
  }

  // ---- epilogue: O /= l, store bf16 ----
  const int qrow = q0 + wave * 16;
  #pragma unroll
  for (int t = 0; t < 16; ++t){
    #pragma unroll
    for (int r = 0; r < 4; ++r){
      float o = of[t][r] / ls[r];
      attnb[((size_t)b * NP + qrow + 4 * hi + r) * ND + 16 * t + lo] = f2bf(o);
    }
  }
}

// ---------------- MLP: Y = [P|attn] @ Wt^T, fused gate epilogue ------------------
__launch_bounds__(256, 2)
__global__ void mlp_kernel(const float* __restrict__ P, const u16* __restrict__ Pbf,
                           const u16* __restrict__ attnb, const u16* __restrict__ Wt,
                           const float* __restrict__ b1, const float* __restrict__ b2,
                           const float* __restrict__ b3, float* __restrict__ out){
  const int m0   = blockIdx.x * 32;
  const int tid  = threadIdx.x;
  const int wave = tid >> 6, lane = tid & 63, lo = lane & 15, hi = lane >> 4;

  __shared__ __align__(16) u16 Xt[32][520];   // 32 rows x 512 (pitch 520)

  #pragma unroll
  for (int it = 0; it < 8; ++it){
    int cc = tid + 256 * it;                  // 32 rows x 64 chunks
    int row = cc >> 6, c8 = cc & 63;
    uint4 v;
    if (c8 < 32) v = *(const uint4*)(Pbf   + ((size_t)(m0 + row)) * ND + c8 * 8);
    else         v = *(const uint4*)(attnb + ((size_t)(m0 + row)) * ND + (c8 - 32) * 8);
    *(uint4*)&Xt[row][c8 * 8] = v;
  }
  __syncthreads();

  f32x4 acc[12][2];
  #pragma unroll
  for (int j = 0; j < 12; ++j){ acc[j][0] = (f32x4){0,0,0,0}; acc[j][1] = (f32x4){0,0,0,0}; }

  for (int c = 0; c < 16; ++c){
    bf16x8 a0 = *(const bf16x8*)&Xt[lo][32 * c + 8 * hi];
    bf16x8 a1 = *(const bf16x8*)&Xt[16 + lo][32 * c + 8 * hi];
    #pragma unroll
    for (int j = 0; j < 12; ++j){
      int n = 16 * (wave + 4 * j) + lo;       // wave-striped n-tiles
      bf16x8 bfr = *(const bf16x8*)(Wt + (size_t)n * 512 + 32 * c + 8 * hi);
      acc[j][0] = __builtin_amdgcn_mfma_f32_16x16x32_bf16(a0, bfr, acc[j][0], 0, 0, 0);
      acc[j][1] = __builtin_amdgcn_mfma_f32_16x16x32_bf16(a1, bfr, acc[j][1], 0, 0, 0);
    }
  }

  #pragma unroll
  for (int mt = 0; mt < 2; ++mt){
    #pragma unroll
    for (int j = 0; j < 4; ++j){
      const int d = 16 * (wave + 4 * j) + lo;
      const float bb1 = b1[d], bb2 = b2[d], bb3 = b3[d];
      #pragma unroll
      for (int r = 0; r < 4; ++r){
        const int row = m0 + 16 * mt + 4 * hi + r;
        float y1 = acc[j][mt][r]     + bb1;
        float y2 = acc[j + 4][mt][r] + bb2;
        float y3 = acc[j + 8][mt][r] + bb3;
        float pv = P[(size_t)row * ND + d];
        float e2 = __expf(2.f * y1);
        float z  = (e2 - 1.f) / (e2 + 1.f);          // tanh
        float rr = 1.f / (1.f + __expf(-y2));        // sigmoid
        float ff = 1.f / (1.f + __expf(-y3));        // sigmoid
        out[(size_t)row * ND + d] = rr * pv + ff * z;
      }
    }
  }
}

extern "C" void kernel_launch(void* const* d_in, const int* in_sizes, int n_in,
                              void* d_out, int out_size, void* d_ws, size_t ws_size,
                              hipStream_t stream){
  const float* P  = (const float*)d_in[0];
  const float* wi = (const float*)d_in[1];
  const float* w1 = (const float*)d_in[2];
  const float* w2 = (const float*)d_in[3];
  const float* w3 = (const float*)d_in[4];
  const float* b1 = (const float*)d_in[5];
  const float* b2 = (const float*)d_in[6];
  const float* b3 = (const float*)d_in[7];
  float* out = (float*)d_out;

  char* ws = (char*)d_ws;
  u16*   Pbf   = (u16*)  (ws);                        // 16 MB
  u16*   PbfT  = (u16*)  (ws + (16u << 20));          // 16 MB
  u16*   attnb = (u16*)  (ws + (32u << 20));          // 16 MB
  u16*   Wt    = (u16*)  (ws + (48u << 20));          // 768 KB
  float* sbv   = (float*)(ws + (49u << 20));          // 128 KB

  prep_rows<<<8192, 256, 0, stream>>>(P, wi, Pbf, sbv);
  prep_w<<<768, 256, 0, stream>>>(w1, w2, w3, Wt);
  transpose_p<<<dim3(16, 4, 32), 256, 0, stream>>>(Pbf, PbfT);
  attn_kernel<<<512, 256, 0, stream>>>(P, wi, Pbf, PbfT, sbv, attnb);
  mlp_kernel<<<1024, 256, 0, stream>>>(P, Pbf, attnb, Wt, b1, b2, b3, out);
}

// Round 3
// 126.746 us; speedup vs baseline: 2.7582x; 1.7010x over previous
//
#include <hip/hip_runtime.h>
#include <hip/hip_bf16.h>

typedef unsigned short u16;
typedef unsigned int   u32;

using bf16x8 = __attribute__((ext_vector_type(8))) short;  // 8 bf16 in 4 VGPRs
using f32x4  = __attribute__((ext_vector_type(4))) float;  // MFMA accumulator

#define NB 32
#define NP 1024
#define ND 256

__device__ __forceinline__ u16 f2bf(float x){
  u32 u = __float_as_uint(x);
  u += 0x7FFFu + ((u >> 16) & 1u);   // round-to-nearest-even
  return (u16)(u >> 16);
}

__device__ __forceinline__ float bf2f(u16 x){
  return __uint_as_float((u32)x << 16);
}

__device__ __forceinline__ void glds16(const void* g, void* l){
  __builtin_amdgcn_global_load_lds((const __attribute__((address_space(1))) void*)g,
                                   (__attribute__((address_space(3))) void*)l, 16, 0, 0);
}

// ---------------- prep 1: Pbf = bf16(P), sbv[row] = P[row,:] . wb ----------------
__global__ void prep_rows(const float* __restrict__ P, const float* __restrict__ wi,
                          u16* __restrict__ Pbf, float* __restrict__ sbv){
  const int row  = blockIdx.x * 4 + (threadIdx.x >> 6);   // one wave per row
  const int lane = threadIdx.x & 63;
  const float4 p  = *(const float4*)(P  + (size_t)row * ND + lane * 4);
  const float4 wb = *(const float4*)(wi + ND + lane * 4);  // wb = wi[256:512]
  ushort4 pb;
  pb.x = f2bf(p.x); pb.y = f2bf(p.y); pb.z = f2bf(p.z); pb.w = f2bf(p.w);
  *(ushort4*)(Pbf + (size_t)row * ND + lane * 4) = pb;
  float s = p.x*wb.x + p.y*wb.y + p.z*wb.z + p.w*wb.w;
  #pragma unroll
  for (int m = 1; m < 64; m <<= 1) s += __shfl_xor(s, m, 64);
  if (lane == 0) sbv[row] = s;
}

// ------- prep 2: pack W fragment-major: Wp[((t*16+c)*64+lane)*8 + e] -------------
// t in [0,48): n = 16t+(lane&15) (t<16 -> w1, <32 -> w2, else w3, col n%256)
// c in [0,16): k = 32c + 8*(lane>>4) + e
__global__ void prep_w(const float* __restrict__ w1, const float* __restrict__ w2,
                       const float* __restrict__ w3, u16* __restrict__ Wp){
  const int t = blockIdx.x;                       // 0..47
  const float* w = (t < 16) ? w1 : ((t < 32) ? w2 : w3);
  const int tid = threadIdx.x;
  #pragma unroll
  for (int j = 0; j < 4; ++j){
    int item = tid + 256 * j;                     // c*64 + lane
    int c = item >> 6, lane = item & 63;
    int ncol = ((t & 15) << 4) + (lane & 15);
    int k0 = 32 * c + 8 * (lane >> 4);
    u16 tmp[8];
    #pragma unroll
    for (int e = 0; e < 8; ++e) tmp[e] = f2bf(w[(size_t)(k0 + e) * 256 + ncol]);
    *(uint4*)(Wp + ((size_t)(t * 16 + c) * 64 + lane) * 8) = *(uint4*)tmp;
  }
}

// ---------------- prep 3: PbfT[b][d][j] = Pbf[b][j][d] (64x64 LDS tiles) ---------
__global__ void transpose_p(const u16* __restrict__ Pbf, u16* __restrict__ PbfT){
  const int b = blockIdx.z, jt = blockIdx.x, dt = blockIdx.y;
  __shared__ u16 T[64][72];
  const int tid = threadIdx.x;
  #pragma unroll
  for (int it = 0; it < 2; ++it){
    int cc = tid + 256 * it;               // 0..511: 64 j-rows x 8 chunks
    int j = cc >> 3, c8 = cc & 7;
    uint4 v = *(const uint4*)(Pbf + ((size_t)b * NP + jt * 64 + j) * ND + dt * 64 + c8 * 8);
    *(uint4*)&T[j][c8 * 8] = v;
  }
  __syncthreads();
  #pragma unroll
  for (int it = 0; it < 2; ++it){
    int cc = tid + 256 * it;               // 64 d-rows x 8 chunks
    int d = cc >> 3, c8 = cc & 7;
    u16 tmp[8];
    #pragma unroll
    for (int k = 0; k < 8; ++k) tmp[k] = T[c8 * 8 + k][d];
    *(uint4*)(PbfT + ((size_t)b * ND + dt * 64 + d) * NP + jt * 64 + c8 * 8) = *(uint4*)tmp;
  }
}

// ---------------- attention: flash-style, QBLK=64 (4 waves x 16 rows), KBLK=64 ---
__launch_bounds__(256, 2)
__global__ void attn_kernel(const float* __restrict__ P, const float* __restrict__ wi,
                            const u16* __restrict__ Pbf, const u16* __restrict__ PbfT,
                            const float* __restrict__ sbv, u16* __restrict__ attnb){
  const int bid  = ((blockIdx.x & 7) << 6) | (blockIdx.x >> 3);  // XCD-contiguous chunks
  const int b    = bid >> 4;
  const int q0   = (bid & 15) << 6;
  const int tid  = threadIdx.x;
  const int wave = tid >> 6, lane = tid & 63, lo = lane & 15, hi = lane >> 4;

  __shared__ __align__(16) u16 KtA[64 * 256];
  __shared__ __align__(16) u16 VtA[256 * 64];
  __shared__ __align__(16) u16 Sp[4][16][72];
  __shared__ float sbt[64];
  char* KtB = (char*)KtA;
  char* VtB = (char*)VtA;

  // ---- Q fragments (A-operand): q = P * wc, bf16, in regs ----
  bf16x8 qf[8];
  {
    const int qrow = q0 + wave * 16 + lo;
    const float* prow = P  + ((size_t)b * NP + qrow) * ND;
    const float* wcp  = wi + 512;
    #pragma unroll
    for (int c = 0; c < 8; ++c){
      const int d0 = 32 * c + 8 * hi;
      float4 a  = *(const float4*)(prow + d0);
      float4 a2 = *(const float4*)(prow + d0 + 4);
      float4 wa  = *(const float4*)(wcp + d0);
      float4 wa2 = *(const float4*)(wcp + d0 + 4);
      bf16x8 q;
      q[0]=(short)f2bf(a.x*wa.x);  q[1]=(short)f2bf(a.y*wa.y);
      q[2]=(short)f2bf(a.z*wa.z);  q[3]=(short)f2bf(a.w*wa.w);
      q[4]=(short)f2bf(a2.x*wa2.x); q[5]=(short)f2bf(a2.y*wa2.y);
      q[6]=(short)f2bf(a2.z*wa2.z); q[7]=(short)f2bf(a2.w*wa2.w);
      qf[c] = q;
    }
  }

  f32x4 of[16];
  #pragma unroll
  for (int t = 0; t < 16; ++t) of[t] = (f32x4){0.f,0.f,0.f,0.f};
  float mx[4] = {-1e30f,-1e30f,-1e30f,-1e30f};
  float ls[4] = {0.f,0.f,0.f,0.f};

  const u16* kslab = Pbf  + (size_t)b * NP * ND;   // row-major [j][d]
  const u16* vslab = PbfT + (size_t)b * ND * NP;   // d-major  [d][j]

  for (int kt = 0; kt < 16; ++kt){
    const int kbase = kt * 64;

    // ---- stage K tile: 8 rounds x (4 waves x 1KB); source pre-swizzled ----
    #pragma unroll
    for (int it = 0; it < 8; ++it){
      int off = it * 4096 + wave * 1024 + lane * 16;        // physical LDS byte
      int row = off >> 9;
      int cl  = (off & 511) ^ ((row & 7) << 4);             // logical byte in row
      const char* g = (const char*)(kslab + (size_t)(kbase + row) * ND) + cl;
      glds16(g, KtB + it * 4096 + wave * 1024);
    }
    // ---- stage V^T tile ----
    #pragma unroll
    for (int it = 0; it < 8; ++it){
      int off = it * 4096 + wave * 1024 + lane * 16;
      int d   = off >> 7;
      int cl  = (off & 127) ^ ((d & 7) << 4);
      const char* g = (const char*)(vslab + (size_t)d * NP + kbase) + cl;
      glds16(g, VtB + it * 4096 + wave * 1024);
    }
    if (tid < 64) sbt[tid] = sbv[(size_t)b * NP + kbase + tid];
    __syncthreads();   // vmcnt(0) drain + barrier: tiles visible

    // ---- S = Q K^T ----
    f32x4 s[4];
    #pragma unroll
    for (int nt = 0; nt < 4; ++nt){
      f32x4 acc = (f32x4){0.f,0.f,0.f,0.f};
      #pragma unroll
      for (int c = 0; c < 8; ++c){
        int row = nt * 16 + lo;
        int pb  = row * 512 + ((64 * c + 16 * hi) ^ ((row & 7) << 4));
        bf16x8 kf = *(const bf16x8*)(KtB + pb);
        acc = __builtin_amdgcn_mfma_f32_16x16x32_bf16(qf[c], kf, acc, 0, 0, 0);
      }
      s[nt] = acc;
    }
    // add sb[j] (sa cancels in softmax)
    #pragma unroll
    for (int nt = 0; nt < 4; ++nt){
      float sv = sbt[nt * 16 + lo];
      #pragma unroll
      for (int r = 0; r < 4; ++r) s[nt][r] += sv;
    }

    // ---- online softmax (row i = 4*hi+r lives across the 16 lo-lanes) ----
    float scale[4];
    #pragma unroll
    for (int r = 0; r < 4; ++r){
      float v = fmaxf(fmaxf(s[0][r], s[1][r]), fmaxf(s[2][r], s[3][r]));
      v = fmaxf(v, __shfl_xor(v, 1, 64));
      v = fmaxf(v, __shfl_xor(v, 2, 64));
      v = fmaxf(v, __shfl_xor(v, 4, 64));
      v = fmaxf(v, __shfl_xor(v, 8, 64));
      float mnew = fmaxf(mx[r], v);
      scale[r] = __expf(mx[r] - mnew);
      mx[r] = mnew;
      float rs = 0.f;
      #pragma unroll
      for (int nt = 0; nt < 4; ++nt){
        float p = __expf(s[nt][r] - mnew);
        s[nt][r] = p; rs += p;
      }
      rs += __shfl_xor(rs, 1, 64);
      rs += __shfl_xor(rs, 2, 64);
      rs += __shfl_xor(rs, 4, 64);
      rs += __shfl_xor(rs, 8, 64);
      ls[r] = ls[r] * scale[r] + rs;
    }
    #pragma unroll
    for (int t = 0; t < 16; ++t){
      #pragma unroll
      for (int r = 0; r < 4; ++r) of[t][r] *= scale[r];
    }
    // repack P-tile (per-wave buffer; within-wave dependency, no barrier needed)
    #pragma unroll
    for (int nt = 0; nt < 4; ++nt)
      #pragma unroll
      for (int r = 0; r < 4; ++r)
        Sp[wave][4 * hi + r][16 * nt + lo] = f2bf(s[nt][r]);

    // ---- O += P V ----
    #pragma unroll
    for (int kk = 0; kk < 2; ++kk){
      bf16x8 pa = *(const bf16x8*)&Sp[wave][lo][32 * kk + 8 * hi];
      #pragma unroll
      for (int t = 0; t < 16; ++t){
        int d  = 16 * t + lo;
        int pb = d * 128 + ((64 * kk + 16 * hi) ^ ((d & 7) << 4));
        bf16x8 vb = *(const bf16x8*)(VtB + pb);
        of[t] = __builtin_amdgcn_mfma_f32_16x16x32_bf16(pa, vb, of[t], 0, 0, 0);
      }
    }
    __syncthreads();   // all waves done reading before next stage overwrites
  }

  // ---- epilogue: O /= l, store bf16 ----
  const int qrow = q0 + wave * 16;
  #pragma unroll
  for (int t = 0; t < 16; ++t){
    #pragma unroll
    for (int r = 0; r < 4; ++r){
      float o = of[t][r] / ls[r];
      attnb[((size_t)b * NP + qrow + 4 * hi + r) * ND + 16 * t + lo] = f2bf(o);
    }
  }
}

// ---------------- MLP: proper GEMM, M-tile 128, fused gate epilogue --------------
// Block (mt,cg): rows [128mt,128mt+128), wave w owns column-triple n=16tq+lo,
// tq = 4cg+w, across w1/w2/w3 (n, n+256, n+512). A double-buffered in LDS
// (XOR-swizzled, staged via global_load_lds); B-frags coalesced from packed Wp.
__launch_bounds__(256, 2)
__global__ void mlp_kernel(const u16* __restrict__ Pbf, const u16* __restrict__ attnb,
                           const u16* __restrict__ Wp,
                           const float* __restrict__ b1, const float* __restrict__ b2,
                           const float* __restrict__ b3, float* __restrict__ out){
  const int p    = blockIdx.x;
  const int swz  = ((p & 7) << 7) | (p >> 3);     // XCD-chunked: same-mt cg's together
  const int mt   = swz >> 2, cg = swz & 3;
  const int tid  = threadIdx.x;
  const int wave = tid >> 6, lane = tid & 63, lo = lane & 15, hi = lane >> 4;
  const int tq   = 4 * cg + wave;
  const int m0   = mt * 128;

  __shared__ __align__(16) u16 Ab[2][128 * 64];   // 2 x 16 KB, swizzled

  f32x4 acc[3][8];
  #pragma unroll
  for (int e = 0; e < 3; ++e)
    #pragma unroll
    for (int m = 0; m < 8; ++m) acc[e][m] = (f32x4){0.f,0.f,0.f,0.f};

  auto stage = [&](int s, int buf){
    const u16* xs = (s < 4) ? (Pbf   + (size_t)m0 * ND + s * 64)
                            : (attnb + (size_t)m0 * ND + (s - 4) * 64);
    char* dst = (char*)Ab[buf];
    #pragma unroll
    for (int it = 0; it < 4; ++it){
      int off = it * 4096 + wave * 1024 + lane * 16;   // physical LDS byte
      int row = off >> 7;                               // 128B per row
      int cl  = (off & 127) ^ ((row & 7) << 4);         // logical byte in row
      glds16((const char*)(xs + (size_t)row * ND) + cl, dst + it * 4096 + wave * 1024);
    }
  };

  stage(0, 0);
  __syncthreads();

  for (int s = 0; s < 8; ++s){
    if (s < 7) stage(s + 1, (s + 1) & 1);
    const char* ab = (const char*)Ab[s & 1];
    #pragma unroll
    for (int cc = 0; cc < 2; ++cc){
      const int c = 2 * s + cc;
      bf16x8 wf[3];
      #pragma unroll
      for (int e = 0; e < 3; ++e)
        wf[e] = *(const bf16x8*)(Wp + ((size_t)((tq + 16 * e) * 16 + c) * 64 + lane) * 8);
      #pragma unroll
      for (int m = 0; m < 8; ++m){
        int row = 16 * m + lo;
        bf16x8 af = *(const bf16x8*)(ab + row * 128 + ((64 * cc + 16 * hi) ^ ((row & 7) << 4)));
        #pragma unroll
        for (int e = 0; e < 3; ++e)
          acc[e][m] = __builtin_amdgcn_mfma_f32_16x16x32_bf16(af, wf[e], acc[e][m], 0, 0, 0);
      }
    }
    __syncthreads();   // drains vmcnt (next buffer staged) + protects buffer reuse
  }

  // ---- fused gate epilogue ----
  const int d = 16 * tq + lo;
  const float bb1 = b1[d], bb2 = b2[d], bb3 = b3[d];
  #pragma unroll
  for (int m = 0; m < 8; ++m){
    #pragma unroll
    for (int r = 0; r < 4; ++r){
      const int row = m0 + 16 * m + 4 * hi + r;
      float y1 = acc[0][m][r] + bb1;
      float y2 = acc[1][m][r] + bb2;
      float y3 = acc[2][m][r] + bb3;
      float pv = bf2f(Pbf[(size_t)row * ND + d]);
      float e2 = __expf(2.f * y1);
      float z  = (e2 - 1.f) / (e2 + 1.f);          // tanh
      float rr = 1.f / (1.f + __expf(-y2));        // sigmoid
      float ff = 1.f / (1.f + __expf(-y3));        // sigmoid
      out[(size_t)row * ND + d] = rr * pv + ff * z;
    }
  }
}

extern "C" void kernel_launch(void* const* d_in, const int* in_sizes, int n_in,
                              void* d_out, int out_size, void* d_ws, size_t ws_size,
                              hipStream_t stream){
  const float* P  = (const float*)d_in[0];
  const float* wi = (const float*)d_in[1];
  const float* w1 = (const float*)d_in[2];
  const float* w2 = (const float*)d_in[3];
  const float* w3 = (const float*)d_in[4];
  const float* b1 = (const float*)d_in[5];
  const float* b2 = (const float*)d_in[6];
  const float* b3 = (const float*)d_in[7];
  float* out = (float*)d_out;

  char* ws = (char*)d_ws;
  u16*   Pbf   = (u16*)  (ws);                        // 16 MB
  u16*   PbfT  = (u16*)  (ws + (16u << 20));          // 16 MB
  u16*   attnb = (u16*)  (ws + (32u << 20));          // 16 MB
  u16*   Wp    = (u16*)  (ws + (48u << 20));          // 768 KB packed fragments
  float* sbv   = (float*)(ws + (49u << 20));          // 128 KB

  prep_rows<<<8192, 256, 0, stream>>>(P, wi, Pbf, sbv);
  prep_w<<<48, 256, 0, stream>>>(w1, w2, w3, Wp);
  transpose_p<<<dim3(16, 4, 32), 256, 0, stream>>>(Pbf, PbfT);
  attn_kernel<<<512, 256, 0, stream>>>(P, wi, Pbf, PbfT, sbv, attnb);
  mlp_kernel<<<1024, 256, 0, stream>>>(Pbf, attnb, Wp, b1, b2, b3, out);
}